// Round 5
// baseline (423.742 us; speedup 1.0000x reference)
//
#include <hip/hip_runtime.h>
#include <hip/hip_bf16.h>

typedef __bf16 bf16x8 __attribute__((ext_vector_type(8)));
typedef float f32x16 __attribute__((ext_vector_type(16)));
typedef unsigned int u32;
typedef unsigned short u16;
typedef u32 u32x4 __attribute__((ext_vector_type(4)));

static constexpr int Nn  = 2048;
static constexpr int DIN = 129;   // in_features = D_IN+1
static constexpr int DO  = 64;    // D_OUT
static constexpr int QP  = 80;    // padded q/k width (65 -> 80)
static constexpr int VR  = 96;    // padded V^T rows (65 -> 96)
static constexpr int AMB = 65;    // ambient dim
static constexpr int XP  = 144;   // padded x row (129 -> 144)
static constexpr int NS  = 4;     // K-splits
static constexpr float LOG2E = 1.4426950408889634f;

#define DEV static __device__ __forceinline__

#if __has_builtin(__builtin_amdgcn_exp2f)
#define FEXP2 __builtin_amdgcn_exp2f
#else
#define FEXP2 exp2f
#endif

DEV u16 f2bf(float f) {
  union { __bf16 h; u16 u; } c;
  c.h = (__bf16)f;
  return c.u;
}
DEV float bf2f(u16 u) {
  union { float f; u32 uu; } c;
  c.uu = ((u32)u) << 16;
  return c.f;
}
DEV u32 cvtpk(float a, float b) {   // low16 = bf16(a), high16 = bf16(b)
  u32 r;
  asm("v_cvt_pk_bf16_f32 %0, %1, %2" : "=v"(r) : "v"(a), "v"(b));
  return r;
}

// ---------------------------------------------------------------------------
// Prep: x (f32 [8192][129]) -> xb (bf16 [8192][144], zero-padded, 16B-aligned)
// ---------------------------------------------------------------------------
__global__ __launch_bounds__(256) void prep_k(const float* __restrict__ x,
                                              u16* __restrict__ xb) {
  const int t = blockIdx.x * 256 + threadIdx.x;   // 0 .. 8192*18-1
  const int row = t / 18, cg = t % 18;
  u16 tmp[8];
#pragma unroll
  for (int j = 0; j < 8; ++j) {
    const int c = cg * 8 + j;
    tmp[j] = (c < DIN) ? f2bf(x[(size_t)row * DIN + c]) : (u16)0;
  }
  u32x4 w;
  w[0] = (u32)tmp[0] | ((u32)tmp[1] << 16);
  w[1] = (u32)tmp[2] | ((u32)tmp[3] << 16);
  w[2] = (u32)tmp[4] | ((u32)tmp[5] << 16);
  w[3] = (u32)tmp[6] | ((u32)tmp[7] << 16);
  *((u32x4*)xb + t) = w;
}

// ---------------------------------------------------------------------------
// Projection: s = xb @ W[h] + b, lift to hyperboloid (C_ATTN=1), store
//   Qb: [bh][n][80] bf16 = alpha' * [qs(64), q0], alpha' = 2*log2e/(scale+eps)
//   Kb: [bh][n][80] bf16 = [ks(64), -(k0-1)]     (centered time: softmax-inv)
//   Vt: [bh][96][n] bf16 = rows 0-63 vs, row 64 v0, rows 65-95 zero
// ---------------------------------------------------------------------------
__global__ __launch_bounds__(256) void proj_k(
    const u16* __restrict__ xb,
    const float* __restrict__ Wq, const float* __restrict__ Wk, const float* __restrict__ Wv,
    const float* __restrict__ bq, const float* __restrict__ bk, const float* __restrict__ bv,
    const float* __restrict__ scale_p,
    u16* __restrict__ Qb, u16* __restrict__ Kb, u16* __restrict__ Vt) {
  __shared__ u16 wt[64][152];       // W^T: [d][k]

  const int tid = threadIdx.x;
  const int wid = tid >> 6, l = tid & 63;
  const int z = blockIdx.y;            // 0..23
  const int T = z >> 3, h = z & 7;     // tensor (0=Q,1=K,2=V), head
  const float* W    = (T == 0 ? Wq : (T == 1 ? Wk : Wv)) + (size_t)h * DIN * DO;
  const float* bias = (T == 0 ? bq : (T == 1 ? bk : bv)) + h * DO;

  {
    const int d = tid & 63, kk = tid >> 6;
    for (int k = kk; k < XP; k += 4)
      wt[d][k] = (k < DIN) ? f2bf(W[(size_t)k * DO + d]) : (u16)0;
  }
  __syncthreads();

  const int lo = l & 31, hi = l >> 5;
  const int row0 = (blockIdx.x * 4 + wid) * 32;
  const u16* xr = xb + (size_t)(row0 + lo) * XP;

  f32x16 acc0 = {}, acc1 = {};
#pragma unroll
  for (int s = 0; s < 9; ++s) {
    bf16x8 a  = *(const bf16x8*)&xr[16 * s + 8 * hi];
    bf16x8 b0 = *(const bf16x8*)&wt[lo][16 * s + 8 * hi];
    bf16x8 b1 = *(const bf16x8*)&wt[32 + lo][16 * s + 8 * hi];
    acc0 = __builtin_amdgcn_mfma_f32_32x32x16_bf16(a, b0, acc0, 0, 0, 0);
    acc1 = __builtin_amdgcn_mfma_f32_32x32x16_bf16(a, b1, acc1, 0, 0, 0);
  }
  const float b0v = bias[lo], b1v = bias[32 + lo];
  const float alpha = 2.0f * LOG2E / (scale_p[0] + 1e-7f);

#pragma unroll
  for (int r = 0; r < 16; ++r) {
    const float s0 = acc0[r] + b0v;
    const float s1 = acc1[r] + b1v;
    float part = s0 * s0 + s1 * s1;
#pragma unroll
    for (int m = 1; m < 32; m <<= 1) part += __shfl_xor(part, m);
    const float time = sqrtf(1.0f + part);     // 1/C_ATTN = 1
    const int dr   = (r & 3) + 8 * (r >> 2) + 4 * hi;
    const int rowg = row0 + dr;
    const int b = rowg >> 11, n = rowg & 2047;
    const int bh = b * 8 + h;
    if (T == 0) {
      u16* q = Qb + ((size_t)bh * Nn + n) * QP;
      q[lo]      = f2bf(alpha * s0);
      q[32 + lo] = f2bf(alpha * s1);
      if (lo == 0)  q[64] = f2bf(alpha * time);
      if (lo < 15)  q[65 + lo] = 0;
    } else if (T == 1) {
      u16* k = Kb + ((size_t)bh * Nn + n) * QP;
      k[lo]      = f2bf(s0);
      k[32 + lo] = f2bf(s1);
      if (lo == 0)  k[64] = f2bf(-(time - 1.0f));
      if (lo < 15)  k[65 + lo] = 0;
    } else {
      u16* v = Vt + (size_t)bh * VR * Nn;
      v[(size_t)lo * Nn + n]        = f2bf(s0);
      v[(size_t)(32 + lo) * Nn + n] = f2bf(s1);
      if (lo == 0) v[(size_t)64 * Nn + n] = f2bf(time);
      if (lo > 0)  v[(size_t)(64 + lo) * Nn + n] = 0;
    }
  }
}

// ---------------------------------------------------------------------------
// One 32-key tile: prefetch next K tile into kn, early-issue V (current),
// QK^T (kc), exp2, cvt_pk + partner exchange, PV.
// ---------------------------------------------------------------------------
DEV void tile_body(const u16* __restrict__ knp, const u16* __restrict__ vk,
                   const int hi,
                   const bf16x8 (&qf)[5], const bf16x8 (&kc)[5], bf16x8 (&kn)[5],
                   f32x16& o0, f32x16& o1, f32x16& o2) {
  // cross-iteration K prefetch (consumed next tile)
#pragma unroll
  for (int s = 0; s < 5; ++s) kn[s] = *(const bf16x8*)&knp[16 * s + 8 * hi];
  // current-tile V, issued early, consumed after softmax (~350 cyc later)
  bf16x8 va[3], vb[3];
#pragma unroll
  for (int t = 0; t < 3; ++t) {
    const u16* vr = vk + (size_t)(32 * t) * Nn;
    va[t] = *(const bf16x8*)&vr[8 * hi];
    vb[t] = *(const bf16x8*)&vr[16 + 8 * hi];
  }
  // QK^T: D[key][q] from registers (no load in chain)
  f32x16 sc = {};
#pragma unroll
  for (int s = 0; s < 5; ++s)
    sc = __builtin_amdgcn_mfma_f32_32x32x16_bf16(kc[s], qf[s], sc, 0, 0, 0);
  // p = 2^score (log2e folded into Q's alpha); no max, no denominator
  float p[16];
#pragma unroll
  for (int r = 0; r < 16; ++r) p[r] = FEXP2(sc[r]);
  // P -> bf16 via v_cvt_pk; partner (lane^32) exchange, send-side select
  u32 wA[4], wB[4];
#pragma unroll
  for (int j = 0; j < 4; ++j) {
    wA[j] = cvtpk(p[2 * j], p[2 * j + 1]);
    wB[j] = cvtpk(p[8 + 2 * j], p[8 + 2 * j + 1]);
  }
  const u32 sA0 = hi ? wA[0] : wA[2], sA1 = hi ? wA[1] : wA[3];
  const u32 sB0 = hi ? wB[0] : wB[2], sB1 = hi ? wB[1] : wB[3];
  const u32 rA0 = (u32)__shfl_xor((int)sA0, 32);
  const u32 rA1 = (u32)__shfl_xor((int)sA1, 32);
  const u32 rB0 = (u32)__shfl_xor((int)sB0, 32);
  const u32 rB1 = (u32)__shfl_xor((int)sB1, 32);
  u32x4 ua = hi ? (u32x4){rA0, rA1, wA[2], wA[3]}
                : (u32x4){wA[0], wA[1], rA0, rA1};
  u32x4 ub = hi ? (u32x4){rB0, rB1, wB[2], wB[3]}
                : (u32x4){wB[0], wB[1], rB0, rB1};
  union { u32x4 u; bf16x8 b; } ca, cb;
  ca.u = ua; cb.u = ub;
  const bf16x8 fA = ca.b;   // keys +0..15
  const bf16x8 fB = cb.b;   // keys +16..31
  // PV: O^T[d][q] += V^T[d][key] * P^T[key][q]
  o0 = __builtin_amdgcn_mfma_f32_32x32x16_bf16(va[0], fA, o0, 0, 0, 0);
  o0 = __builtin_amdgcn_mfma_f32_32x32x16_bf16(vb[0], fB, o0, 0, 0, 0);
  o1 = __builtin_amdgcn_mfma_f32_32x32x16_bf16(va[1], fA, o1, 0, 0, 0);
  o1 = __builtin_amdgcn_mfma_f32_32x32x16_bf16(vb[1], fB, o1, 0, 0, 0);
  o2 = __builtin_amdgcn_mfma_f32_32x32x16_bf16(va[2], fA, o2, 0, 0, 0);
  o2 = __builtin_amdgcn_mfma_f32_32x32x16_bf16(vb[2], fB, o2, 0, 0, 0);
}

// ---------------------------------------------------------------------------
// Attention (no-max softmax; scale-invariant normalize -> no denominator).
// 1 wave = 32 q, swapped QK^T. XCD-chunked swizzle. S=4 K-splits.
// Partials (bf16): part[bh*4+s][65][n].
// ---------------------------------------------------------------------------
__global__ __launch_bounds__(256) void attn_k(
    const u16* __restrict__ Qb, const u16* __restrict__ Kb,
    const u16* __restrict__ Vt, u16* __restrict__ part) {
  const int tid  = threadIdx.x;
  const int w    = tid >> 6, lane = tid & 63;
  const int lo   = lane & 31, hi = lane >> 5;

  // XCD-chunked swizzle (2048 blocks, 8 XCDs, bijective)
  const u32 bid = blockIdx.x;
  const u32 swz = (bid & 7) * 256 + (bid >> 3);
  const int bh   = swz >> 6;
  const int sidx = (swz >> 4) & 3;
  const int qt   = swz & 15;
  const int qbase = qt * 128 + w * 32;

  const u16* qrow = Qb + ((size_t)bh * Nn + qbase + lo) * QP;
  bf16x8 qf[5];
#pragma unroll
  for (int s = 0; s < 5; ++s) qf[s] = *(const bf16x8*)&qrow[16 * s + 8 * hi];

  f32x16 o0 = {}, o1 = {}, o2 = {};   // O^T rows d = 0..31, 32..63, 64..95
  const u16* kb_p = Kb + (size_t)bh * Nn * QP;
  const u16* vb_p = Vt + (size_t)bh * VR * Nn;
  const int k0i = sidx * (Nn / NS);

  const u16* kpl = kb_p + ((size_t)k0i + lo) * QP;   // current K tile, this lane's row
  const u16* vkl = vb_p + (size_t)lo * Nn + k0i;     // V tile base, this lane's row
  bf16x8 kA[5], kB[5];
#pragma unroll
  for (int s = 0; s < 5; ++s) kA[s] = *(const bf16x8*)&kpl[16 * s + 8 * hi];

  for (int it = 0; it < (Nn / NS) / 64; ++it) {
    tile_body(kpl + 32 * QP, vkl,      hi, qf, kA, kB, o0, o1, o2);
    tile_body(kpl + 64 * QP, vkl + 32, hi, qf, kB, kA, o0, o1, o2);
    kpl += 64 * QP;
    vkl += 64;
  }

  // write raw partial O^T (finale combines + normalizes)
  const int q = qbase + lo;
  u16* po = part + ((size_t)(bh * NS + sidx) * AMB) * Nn;
#pragma unroll
  for (int r = 0; r < 16; ++r) {
    const int dr = (r & 3) + 8 * (r >> 2) + 4 * hi;
    po[(size_t)dr * Nn + q]        = f2bf(o0[r]);
    po[(size_t)(32 + dr) * Nn + q] = f2bf(o1[r]);
  }
  if (hi == 0) po[(size_t)64 * Nn + q] = f2bf(o2[0]);
}

// ---------------------------------------------------------------------------
// Finale: combine splits + per-head Lorentz normalize + head-sum + final
// normalize + re-lift (C_ATTN=C_OUT=1). One thread per (b,n) row.
// ---------------------------------------------------------------------------
__global__ __launch_bounds__(64) void finale_k(const u16* __restrict__ part,
                                               float* __restrict__ out) {
  const int g = blockIdx.x * 64 + threadIdx.x;    // 0..8191 = b*2048+n
  const int b = g >> 11, n = g & 2047;

  float sum[AMB];
#pragma unroll
  for (int d = 0; d < AMB; ++d) sum[d] = 0.f;

  for (int h = 0; h < 8; ++h) {
    const u16* p0 = part + ((size_t)(b * 8 + h) * NS * AMB) * Nn + n;
    float Oh[AMB];
#pragma unroll
    for (int d = 0; d < AMB; ++d) {
      float v = bf2f(p0[(size_t)d * Nn]);
      v += bf2f(p0[(size_t)(AMB + d) * Nn]);
      v += bf2f(p0[(size_t)(2 * AMB + d) * Nn]);
      v += bf2f(p0[(size_t)(3 * AMB + d) * Nn]);
      Oh[d] = v;
    }
    float ss = 0.f;
#pragma unroll
    for (int d = 0; d < 64; ++d) ss += Oh[d] * Oh[d];
    const float tm  = Oh[64];
    const float inv = rsqrtf(fmaxf(tm * tm - ss, 1e-7f));
#pragma unroll
    for (int d = 0; d < AMB; ++d) sum[d] += Oh[d] * inv;
  }

  float ss = 0.f;
#pragma unroll
  for (int d = 0; d < 64; ++d) ss += sum[d] * sum[d];
  const float tm  = sum[64];
  const float inv = rsqrtf(fmaxf(tm * tm - ss, 1e-7f));
  const float ssp = ss * inv * inv;               // ||spatial_out||^2
  float* o = out + (size_t)g * AMB;
  o[0] = sqrtf(1.0f + ssp);
#pragma unroll
  for (int d = 0; d < 64; ++d) o[1 + d] = sum[d] * inv;
}

// ---------------------------------------------------------------------------
extern "C" void kernel_launch(void* const* d_in, const int* in_sizes, int n_in,
                              void* d_out, int out_size, void* d_ws, size_t ws_size,
                              hipStream_t stream) {
  (void)in_sizes; (void)n_in; (void)out_size; (void)ws_size;
  const float* x  = (const float*)d_in[0];
  const float* Wq = (const float*)d_in[1];
  const float* Wk = (const float*)d_in[2];
  const float* Wv = (const float*)d_in[3];
  const float* bq = (const float*)d_in[4];
  const float* bk = (const float*)d_in[5];
  const float* bv = (const float*)d_in[6];
  const float* sc = (const float*)d_in[7];
  // d_in[8] = attn_bias: uniform additive score offset -> softmax-invariant.

  char* ws = (char*)d_ws;
  u16*  Qb = (u16*)(ws);                  // 10,485,760 B
  u16*  Kb = (u16*)(ws + 10485760);       // 10,485,760 B
  u16*  Vt = (u16*)(ws + 20971520);       // 12,582,912 B
  u16*  pb = (u16*)(ws + 33554432);       // bf16 partials: 34,078,720 B
  u16*  xb = (u16*)(ws + 33554432);       // 2,359,296 B, dead before attn_k
  float* out = (float*)d_out;

  hipLaunchKernelGGL(prep_k, dim3(576), dim3(256), 0, stream, x, xb);
  hipLaunchKernelGGL(proj_k, dim3(64, 24), dim3(256), 0, stream,
                     xb, Wq, Wk, Wv, bq, bk, bv, sc, Qb, Kb, Vt);
  hipLaunchKernelGGL(attn_k, dim3(2048), dim3(256), 0, stream, Qb, Kb, Vt, pb);
  hipLaunchKernelGGL(finale_k, dim3(128), dim3(64), 0, stream, pb, out);
}

// Round 7
// 177.687 us; speedup vs baseline: 2.3848x; 2.3848x over previous
//
#include <hip/hip_runtime.h>
#include <hip/hip_bf16.h>

typedef __bf16 bf16x8 __attribute__((ext_vector_type(8)));
typedef float f32x16 __attribute__((ext_vector_type(16)));
typedef unsigned int u32;
typedef unsigned short u16;
typedef u32 u32x2 __attribute__((ext_vector_type(2)));
typedef u32 u32x4 __attribute__((ext_vector_type(4)));

static constexpr int Nn  = 2048;
static constexpr int DIN = 129;   // in_features = D_IN+1
static constexpr int DO  = 64;    // D_OUT
static constexpr int QP  = 80;    // padded q/k width (65 -> 80)
static constexpr int VR  = 96;    // padded V^T rows (65 -> 96)
static constexpr int AMB = 65;    // ambient dim
static constexpr int XP  = 144;   // padded x row (129 -> 144)
static constexpr int NS  = 4;     // K-splits
static constexpr int PR  = 72;    // partial row pad (65 -> 72), 144 B
static constexpr float LOG2E = 1.4426950408889634f;

#define DEV static __device__ __forceinline__

#if __has_builtin(__builtin_amdgcn_exp2f)
#define FEXP2 __builtin_amdgcn_exp2f
#else
#define FEXP2 exp2f
#endif

DEV u16 f2bf(float f) {
  union { __bf16 h; u16 u; } c;
  c.h = (__bf16)f;
  return c.u;
}
DEV float bf2f(u16 u) {
  union { float f; u32 uu; } c;
  c.uu = ((u32)u) << 16;
  return c.f;
}
DEV u32 cvtpk(float a, float b) {   // low16 = bf16(a), high16 = bf16(b)
  u32 r;
  asm("v_cvt_pk_bf16_f32 %0, %1, %2" : "=v"(r) : "v"(a), "v"(b));
  return r;
}

// ---------------------------------------------------------------------------
// Prep: x (f32 [8192][129]) -> xb (bf16 [8192][144], zero-padded, 16B-aligned)
// ---------------------------------------------------------------------------
__global__ __launch_bounds__(256) void prep_k(const float* __restrict__ x,
                                              u16* __restrict__ xb) {
  const int t = blockIdx.x * 256 + threadIdx.x;   // 0 .. 8192*18-1
  const int row = t / 18, cg = t % 18;
  u16 tmp[8];
#pragma unroll
  for (int j = 0; j < 8; ++j) {
    const int c = cg * 8 + j;
    tmp[j] = (c < DIN) ? f2bf(x[(size_t)row * DIN + c]) : (u16)0;
  }
  u32x4 w;
  w[0] = (u32)tmp[0] | ((u32)tmp[1] << 16);
  w[1] = (u32)tmp[2] | ((u32)tmp[3] << 16);
  w[2] = (u32)tmp[4] | ((u32)tmp[5] << 16);
  w[3] = (u32)tmp[6] | ((u32)tmp[7] << 16);
  *((u32x4*)xb + t) = w;
}

// ---------------------------------------------------------------------------
// Projection: s = xb @ W[h] + b, lift to hyperboloid (C_ATTN=1), store
//   Qb: [bh][n][80] bf16 = alpha' * [qs(64), q0], alpha' = 2*log2e/(scale+eps)
//   Kb: [bh][n][80] bf16 = [ks(64), -(k0-1)]     (centered time: softmax-inv)
//   Vt: [bh][96][n] bf16 = rows 0-63 vs, row 64 v0, rows 65-95 zero
// ---------------------------------------------------------------------------
__global__ __launch_bounds__(256) void proj_k(
    const u16* __restrict__ xb,
    const float* __restrict__ Wq, const float* __restrict__ Wk, const float* __restrict__ Wv,
    const float* __restrict__ bq, const float* __restrict__ bk, const float* __restrict__ bv,
    const float* __restrict__ scale_p,
    u16* __restrict__ Qb, u16* __restrict__ Kb, u16* __restrict__ Vt) {
  __shared__ u16 wt[64][152];       // W^T: [d][k]

  const int tid = threadIdx.x;
  const int wid = tid >> 6, l = tid & 63;
  const int z = blockIdx.y;            // 0..23
  const int T = z >> 3, h = z & 7;     // tensor (0=Q,1=K,2=V), head
  const float* W    = (T == 0 ? Wq : (T == 1 ? Wk : Wv)) + (size_t)h * DIN * DO;
  const float* bias = (T == 0 ? bq : (T == 1 ? bk : bv)) + h * DO;

  {
    const int d = tid & 63, kk = tid >> 6;
    for (int k = kk; k < XP; k += 4)
      wt[d][k] = (k < DIN) ? f2bf(W[(size_t)k * DO + d]) : (u16)0;
  }
  __syncthreads();

  const int lo = l & 31, hi = l >> 5;
  const int row0 = (blockIdx.x * 4 + wid) * 32;
  const u16* xr = xb + (size_t)(row0 + lo) * XP;

  f32x16 acc0 = {}, acc1 = {};
#pragma unroll
  for (int s = 0; s < 9; ++s) {
    bf16x8 a  = *(const bf16x8*)&xr[16 * s + 8 * hi];
    bf16x8 b0 = *(const bf16x8*)&wt[lo][16 * s + 8 * hi];
    bf16x8 b1 = *(const bf16x8*)&wt[32 + lo][16 * s + 8 * hi];
    acc0 = __builtin_amdgcn_mfma_f32_32x32x16_bf16(a, b0, acc0, 0, 0, 0);
    acc1 = __builtin_amdgcn_mfma_f32_32x32x16_bf16(a, b1, acc1, 0, 0, 0);
  }
  const float b0v = bias[lo], b1v = bias[32 + lo];
  const float alpha = 2.0f * LOG2E / (scale_p[0] + 1e-7f);

#pragma unroll
  for (int r = 0; r < 16; ++r) {
    const float s0 = acc0[r] + b0v;
    const float s1 = acc1[r] + b1v;
    float part = s0 * s0 + s1 * s1;
#pragma unroll
    for (int m = 1; m < 32; m <<= 1) part += __shfl_xor(part, m);
    const float time = sqrtf(1.0f + part);     // 1/C_ATTN = 1
    const int dr   = (r & 3) + 8 * (r >> 2) + 4 * hi;
    const int rowg = row0 + dr;
    const int b = rowg >> 11, n = rowg & 2047;
    const int bh = b * 8 + h;
    if (T == 0) {
      u16* q = Qb + ((size_t)bh * Nn + n) * QP;
      q[lo]      = f2bf(alpha * s0);
      q[32 + lo] = f2bf(alpha * s1);
      if (lo == 0)  q[64] = f2bf(alpha * time);
      if (lo < 15)  q[65 + lo] = 0;
    } else if (T == 1) {
      u16* k = Kb + ((size_t)bh * Nn + n) * QP;
      k[lo]      = f2bf(s0);
      k[32 + lo] = f2bf(s1);
      if (lo == 0)  k[64] = f2bf(-(time - 1.0f));
      if (lo < 15)  k[65 + lo] = 0;
    } else {
      u16* v = Vt + (size_t)bh * VR * Nn;
      v[(size_t)lo * Nn + n]        = f2bf(s0);
      v[(size_t)(32 + lo) * Nn + n] = f2bf(s1);
      if (lo == 0) v[(size_t)64 * Nn + n] = f2bf(time);
      if (lo > 0)  v[(size_t)(64 + lo) * Nn + n] = 0;
    }
  }
}

// ---------------------------------------------------------------------------
// One 32-key tile: prefetch next K tile into kn, early-issue V (current),
// QK^T (kc), exp2, cvt_pk + partner exchange, PV.
// ---------------------------------------------------------------------------
DEV void tile_body(const u16* __restrict__ knp, const u16* __restrict__ vk,
                   const int hi,
                   const bf16x8 (&qf)[5], const bf16x8 (&kc)[5], bf16x8 (&kn)[5],
                   f32x16& o0, f32x16& o1, f32x16& o2) {
  // cross-iteration K prefetch (consumed next tile)
#pragma unroll
  for (int s = 0; s < 5; ++s) kn[s] = *(const bf16x8*)&knp[16 * s + 8 * hi];
  // current-tile V, issued early, consumed after softmax (~350 cyc later)
  bf16x8 va[3], vb[3];
#pragma unroll
  for (int t = 0; t < 3; ++t) {
    const u16* vr = vk + (size_t)(32 * t) * Nn;
    va[t] = *(const bf16x8*)&vr[8 * hi];
    vb[t] = *(const bf16x8*)&vr[16 + 8 * hi];
  }
  // QK^T: D[key][q] from registers (no load in chain)
  f32x16 sc = {};
#pragma unroll
  for (int s = 0; s < 5; ++s)
    sc = __builtin_amdgcn_mfma_f32_32x32x16_bf16(kc[s], qf[s], sc, 0, 0, 0);
  // p = 2^score (log2e folded into Q's alpha); no max, no denominator
  float p[16];
#pragma unroll
  for (int r = 0; r < 16; ++r) p[r] = FEXP2(sc[r]);
  // P -> bf16 via v_cvt_pk; partner (lane^32) exchange, send-side select
  u32 wA[4], wB[4];
#pragma unroll
  for (int j = 0; j < 4; ++j) {
    wA[j] = cvtpk(p[2 * j], p[2 * j + 1]);
    wB[j] = cvtpk(p[8 + 2 * j], p[8 + 2 * j + 1]);
  }
  const u32 sA0 = hi ? wA[0] : wA[2], sA1 = hi ? wA[1] : wA[3];
  const u32 sB0 = hi ? wB[0] : wB[2], sB1 = hi ? wB[1] : wB[3];
  const u32 rA0 = (u32)__shfl_xor((int)sA0, 32);
  const u32 rA1 = (u32)__shfl_xor((int)sA1, 32);
  const u32 rB0 = (u32)__shfl_xor((int)sB0, 32);
  const u32 rB1 = (u32)__shfl_xor((int)sB1, 32);
  u32x4 ua = hi ? (u32x4){rA0, rA1, wA[2], wA[3]}
                : (u32x4){wA[0], wA[1], rA0, rA1};
  u32x4 ub = hi ? (u32x4){rB0, rB1, wB[2], wB[3]}
                : (u32x4){wB[0], wB[1], rB0, rB1};
  union { u32x4 u; bf16x8 b; } ca, cb;
  ca.u = ua; cb.u = ub;
  const bf16x8 fA = ca.b;   // keys +0..15
  const bf16x8 fB = cb.b;   // keys +16..31
  // PV: O^T[d][q] += V^T[d][key] * P^T[key][q]
  o0 = __builtin_amdgcn_mfma_f32_32x32x16_bf16(va[0], fA, o0, 0, 0, 0);
  o0 = __builtin_amdgcn_mfma_f32_32x32x16_bf16(vb[0], fB, o0, 0, 0, 0);
  o1 = __builtin_amdgcn_mfma_f32_32x32x16_bf16(va[1], fA, o1, 0, 0, 0);
  o1 = __builtin_amdgcn_mfma_f32_32x32x16_bf16(vb[1], fB, o1, 0, 0, 0);
  o2 = __builtin_amdgcn_mfma_f32_32x32x16_bf16(va[2], fA, o2, 0, 0, 0);
  o2 = __builtin_amdgcn_mfma_f32_32x32x16_bf16(vb[2], fB, o2, 0, 0, 0);
}

// ---------------------------------------------------------------------------
// Attention (no-max softmax; scale-invariant normalize -> no denominator).
// 1 wave = 32 q, swapped QK^T. XCD-chunked swizzle. S=4 K-splits.
// Partials (bf16, d-contiguous): part[(bh*4+s)*2048 + n][72].
// ---------------------------------------------------------------------------
__global__ __launch_bounds__(256) void attn_k(
    const u16* __restrict__ Qb, const u16* __restrict__ Kb,
    const u16* __restrict__ Vt, u16* __restrict__ part) {
  const int tid  = threadIdx.x;
  const int w    = tid >> 6, lane = tid & 63;
  const int lo   = lane & 31, hi = lane >> 5;

  // XCD-chunked swizzle (2048 blocks, 8 XCDs, bijective)
  const u32 bid = blockIdx.x;
  const u32 swz = (bid & 7) * 256 + (bid >> 3);
  const int bh   = swz >> 6;
  const int sidx = (swz >> 4) & 3;
  const int qt   = swz & 15;
  const int qbase = qt * 128 + w * 32;

  const u16* qrow = Qb + ((size_t)bh * Nn + qbase + lo) * QP;
  bf16x8 qf[5];
#pragma unroll
  for (int s = 0; s < 5; ++s) qf[s] = *(const bf16x8*)&qrow[16 * s + 8 * hi];

  f32x16 o0 = {}, o1 = {}, o2 = {};   // O^T rows d = 0..31, 32..63, 64..95
  const u16* kb_p = Kb + (size_t)bh * Nn * QP;
  const u16* vb_p = Vt + (size_t)bh * VR * Nn;
  const int k0i = sidx * (Nn / NS);

  const u16* kpl = kb_p + ((size_t)k0i + lo) * QP;   // current K tile, this lane's row
  const u16* vkl = vb_p + (size_t)lo * Nn + k0i;     // V tile base, this lane's row
  bf16x8 kA[5], kB[5];
#pragma unroll
  for (int s = 0; s < 5; ++s) kA[s] = *(const bf16x8*)&kpl[16 * s + 8 * hi];

  for (int it = 0; it < (Nn / NS) / 64; ++it) {
    tile_body(kpl + 32 * QP, vkl,      hi, qf, kA, kB, o0, o1, o2);
    tile_body(kpl + 64 * QP, vkl + 32, hi, qf, kB, kA, o0, o1, o2);
    kpl += 64 * QP;
    vkl += 64;
  }

  // write raw partial O^T, d-contiguous rows: lane owns q = qbase+lo.
  // o0[4t..4t+3] -> d = 8t+4hi+{0..3}; o1 same +32; o2[0] -> d=64 (hi==0).
  const int q = qbase + lo;
  u16* po = part + ((size_t)((bh * NS + sidx) * Nn + q)) * PR;
#pragma unroll
  for (int t = 0; t < 4; ++t) {
    const u32 a0 = cvtpk(o0[4 * t], o0[4 * t + 1]);
    const u32 a1 = cvtpk(o0[4 * t + 2], o0[4 * t + 3]);
    const u32 b0 = cvtpk(o1[4 * t], o1[4 * t + 1]);
    const u32 b1 = cvtpk(o1[4 * t + 2], o1[4 * t + 3]);
    *(u32x2*)&po[8 * t + 4 * hi]      = (u32x2){a0, a1};
    *(u32x2*)&po[8 * t + 4 * hi + 32] = (u32x2){b0, b1};
  }
  if (hi == 0) po[64] = f2bf(o2[0]);
}

// ---------------------------------------------------------------------------
// Finale (wave-cooperative): one wave per (b,n). Lane l -> (h = l>>3, chunk
// c = l&7 covering d = 8c..8c+7). Combine 4 splits, per-head Lorentz
// normalize (shfl_xor 1,2,4 within h-group), head-sum (shfl_xor 8,16,32),
// final normalize + re-lift. No register arrays, no spills.
// ---------------------------------------------------------------------------
__global__ __launch_bounds__(256) void finale_k(const u16* __restrict__ part,
                                                float* __restrict__ out) {
  const int tid = threadIdx.x;
  const int wv = tid >> 6, l = tid & 63;
  const int g = blockIdx.x * 4 + wv;       // 0..8191 = b*2048+n
  const int b = g >> 11, n = g & 2047;
  const int h = l >> 3, c = l & 7;

  const u16* rowp = part + ((size_t)((b * 8 + h) * NS) * Nn + n) * PR;
  float Oh[8];
#pragma unroll
  for (int j = 0; j < 8; ++j) Oh[j] = 0.f;
  float th = 0.f;
#pragma unroll
  for (int s = 0; s < NS; ++s) {
    const u16* rp = rowp + (size_t)s * Nn * PR;
    const u32x4 v = *(const u32x4*)&rp[8 * c];
#pragma unroll
    for (int i = 0; i < 4; ++i) {
      union { u32 u; float f; } a, bb;
      a.u  = v[i] << 16;
      bb.u = v[i] & 0xffff0000u;
      Oh[2 * i]     += a.f;
      Oh[2 * i + 1] += bb.f;
    }
    th += bf2f(rp[64]);                    // broadcast within h-group
  }

  // per-head ||spatial||^2 across the 8 chunks of this h-group
  float sq = 0.f;
#pragma unroll
  for (int j = 0; j < 8; ++j) sq += Oh[j] * Oh[j];
  sq += __shfl_xor(sq, 1);
  sq += __shfl_xor(sq, 2);
  sq += __shfl_xor(sq, 4);
  const float invh = rsqrtf(fmaxf(th * th - sq, 1e-7f));

  // normalized mid, then sum across heads (lanes with same c, different h)
  float S[8];
#pragma unroll
  for (int j = 0; j < 8; ++j) S[j] = Oh[j] * invh;
  float T = th * invh;
#pragma unroll
  for (int m = 8; m <= 32; m <<= 1) {
#pragma unroll
    for (int j = 0; j < 8; ++j) S[j] += __shfl_xor(S[j], m);
    T += __shfl_xor(T, m);
  }

  // final Lorentz normalize + re-lift (C_ATTN=C_OUT=1)
  float s2 = 0.f;
#pragma unroll
  for (int j = 0; j < 8; ++j) s2 += S[j] * S[j];
  s2 += __shfl_xor(s2, 1);
  s2 += __shfl_xor(s2, 2);
  s2 += __shfl_xor(s2, 4);
  const float inv = rsqrtf(fmaxf(T * T - s2, 1e-7f));
  const float ssp = s2 * inv * inv;        // ||spatial_out||^2

  float* o = out + (size_t)g * AMB;
  if (h == 0) {
#pragma unroll
    for (int j = 0; j < 8; ++j) o[1 + 8 * c + j] = S[j] * inv;
    if (l == 0) o[0] = sqrtf(1.0f + ssp);
  }
}

// ---------------------------------------------------------------------------
extern "C" void kernel_launch(void* const* d_in, const int* in_sizes, int n_in,
                              void* d_out, int out_size, void* d_ws, size_t ws_size,
                              hipStream_t stream) {
  (void)in_sizes; (void)n_in; (void)out_size; (void)ws_size;
  const float* x  = (const float*)d_in[0];
  const float* Wq = (const float*)d_in[1];
  const float* Wk = (const float*)d_in[2];
  const float* Wv = (const float*)d_in[3];
  const float* bq = (const float*)d_in[4];
  const float* bk = (const float*)d_in[5];
  const float* bv = (const float*)d_in[6];
  const float* sc = (const float*)d_in[7];
  // d_in[8] = attn_bias: uniform additive score offset -> softmax-invariant.

  char* ws = (char*)d_ws;
  u16*  Qb = (u16*)(ws);                  // 10,485,760 B
  u16*  Kb = (u16*)(ws + 10485760);       // 10,485,760 B
  u16*  Vt = (u16*)(ws + 20971520);       // 12,582,912 B
  u16*  pb = (u16*)(ws + 33554432);       // bf16 partials: 37,748,736 B (d-contig)
  u16*  xb = (u16*)(ws + 33554432);       // 2,359,296 B, dead before attn_k
  float* out = (float*)d_out;

  hipLaunchKernelGGL(prep_k, dim3(576), dim3(256), 0, stream, x, xb);
  hipLaunchKernelGGL(proj_k, dim3(64, 24), dim3(256), 0, stream,
                     xb, Wq, Wk, Wv, bq, bk, bv, sc, Qb, Kb, Vt);
  hipLaunchKernelGGL(attn_k, dim3(2048), dim3(256), 0, stream, Qb, Kb, Vt, pb);
  // 8192 (b,n) rows, 4 waves/block -> 2048 blocks (r6 bug: was 512 -> 3/4 of
  // the output never written)
  hipLaunchKernelGGL(finale_k, dim3(2048), dim3(256), 0, stream, pb, out);
}

// Round 8
// 120.189 us; speedup vs baseline: 3.5256x; 1.4784x over previous
//
#include <hip/hip_runtime.h>
#include <hip/hip_bf16.h>

typedef __bf16 bf16x8 __attribute__((ext_vector_type(8)));
typedef float f32x16 __attribute__((ext_vector_type(16)));
typedef unsigned int u32;
typedef unsigned short u16;
typedef u32 u32x2 __attribute__((ext_vector_type(2)));
typedef u32 u32x4 __attribute__((ext_vector_type(4)));

static constexpr int Nn  = 2048;
static constexpr int DIN = 129;   // in_features = D_IN+1
static constexpr int DO  = 64;    // D_OUT
static constexpr int QP  = 80;    // padded q/k width (65 -> 80)
static constexpr int AMB = 65;    // ambient dim
static constexpr int XP  = 144;   // padded x row (129 -> 144)
static constexpr int NS  = 4;     // K-splits
static constexpr int PR  = 72;    // partial row pad (65 -> 72), 144 B
// Tiled K/V global layouts == LDS image (gload_lds linear-dest constraint):
static constexpr int KROW = 88;   // K tile row, u16 (176 B, 16B-aligned, uniform banks)
static constexpr int KTS  = 3072; // K tile size, u16 (6144 B = 6 x 1024B insts)
static constexpr int VROW = 40;   // V tile row, u16 (80 B, 16B-aligned, uniform banks)
static constexpr int VTS  = 4096; // V tile size, u16 (8192 B = 8 x 1024B insts)
static constexpr float LOG2E = 1.4426950408889634f;

#define DEV static __device__ __forceinline__

#if __has_builtin(__builtin_amdgcn_exp2f)
#define FEXP2 __builtin_amdgcn_exp2f
#else
#define FEXP2 exp2f
#endif

DEV u16 f2bf(float f) {
  union { __bf16 h; u16 u; } c;
  c.h = (__bf16)f;
  return c.u;
}
DEV float bf2f(u16 u) {
  union { float f; u32 uu; } c;
  c.uu = ((u32)u) << 16;
  return c.f;
}
DEV u32 cvtpk(float a, float b) {   // low16 = bf16(a), high16 = bf16(b)
  u32 r;
  asm("v_cvt_pk_bf16_f32 %0, %1, %2" : "=v"(r) : "v"(a), "v"(b));
  return r;
}
DEV void gload_lds16(const u16* g, u16* l) {   // 64 lanes x 16B -> 1024B linear LDS
  __builtin_amdgcn_global_load_lds(
      (const __attribute__((address_space(1))) unsigned int*)g,
      (__attribute__((address_space(3))) unsigned int*)l, 16, 0, 0);
}

// ---------------------------------------------------------------------------
// Prep: x (f32 [8192][129]) -> xb (bf16 [8192][144], zero-padded, 16B-aligned)
// ---------------------------------------------------------------------------
__global__ __launch_bounds__(256) void prep_k(const float* __restrict__ x,
                                              u16* __restrict__ xb) {
  const int t = blockIdx.x * 256 + threadIdx.x;   // 0 .. 8192*18-1
  const int row = t / 18, cg = t % 18;
  u16 tmp[8];
#pragma unroll
  for (int j = 0; j < 8; ++j) {
    const int c = cg * 8 + j;
    tmp[j] = (c < DIN) ? f2bf(x[(size_t)row * DIN + c]) : (u16)0;
  }
  u32x4 w;
  w[0] = (u32)tmp[0] | ((u32)tmp[1] << 16);
  w[1] = (u32)tmp[2] | ((u32)tmp[3] << 16);
  w[2] = (u32)tmp[4] | ((u32)tmp[5] << 16);
  w[3] = (u32)tmp[6] | ((u32)tmp[7] << 16);
  *((u32x4*)xb + t) = w;
}

// ---------------------------------------------------------------------------
// Projection: s = xb @ W[h] + b, lift to hyperboloid (C_ATTN=1), store
//   Qb:  [bh][n][80] bf16 = alpha' * [qs(64), q0], alpha' = 2*log2e/(scale+eps)
//   Ktl: [bh][tile=n>>5][key=n&31][88] bf16 = [ks(64), -(k0-1), 0*15, pad]
//   Vtl: [bh][tile=n>>5][dim][40]   bf16 = col n&31; dims 0-63 vs, 64 v0
// ---------------------------------------------------------------------------
__global__ __launch_bounds__(256) void proj_k(
    const u16* __restrict__ xb,
    const float* __restrict__ Wq, const float* __restrict__ Wk, const float* __restrict__ Wv,
    const float* __restrict__ bq, const float* __restrict__ bk, const float* __restrict__ bv,
    const float* __restrict__ scale_p,
    u16* __restrict__ Qb, u16* __restrict__ Ktl, u16* __restrict__ Vtl) {
  __shared__ u16 wt[64][152];       // W^T: [d][k]

  const int tid = threadIdx.x;
  const int wid = tid >> 6, l = tid & 63;
  const int z = blockIdx.y;            // 0..23
  const int T = z >> 3, h = z & 7;     // tensor (0=Q,1=K,2=V), head
  const float* W    = (T == 0 ? Wq : (T == 1 ? Wk : Wv)) + (size_t)h * DIN * DO;
  const float* bias = (T == 0 ? bq : (T == 1 ? bk : bv)) + h * DO;

  {
    const int d = tid & 63, kk = tid >> 6;
    for (int k = kk; k < XP; k += 4)
      wt[d][k] = (k < DIN) ? f2bf(W[(size_t)k * DO + d]) : (u16)0;
  }
  __syncthreads();

  const int lo = l & 31, hi = l >> 5;
  const int row0 = (blockIdx.x * 4 + wid) * 32;
  const u16* xr = xb + (size_t)(row0 + lo) * XP;

  f32x16 acc0 = {}, acc1 = {};
#pragma unroll
  for (int s = 0; s < 9; ++s) {
    bf16x8 a  = *(const bf16x8*)&xr[16 * s + 8 * hi];
    bf16x8 b0 = *(const bf16x8*)&wt[lo][16 * s + 8 * hi];
    bf16x8 b1 = *(const bf16x8*)&wt[32 + lo][16 * s + 8 * hi];
    acc0 = __builtin_amdgcn_mfma_f32_32x32x16_bf16(a, b0, acc0, 0, 0, 0);
    acc1 = __builtin_amdgcn_mfma_f32_32x32x16_bf16(a, b1, acc1, 0, 0, 0);
  }
  const float b0v = bias[lo], b1v = bias[32 + lo];
  const float alpha = 2.0f * LOG2E / (scale_p[0] + 1e-7f);

#pragma unroll
  for (int r = 0; r < 16; ++r) {
    const float s0 = acc0[r] + b0v;
    const float s1 = acc1[r] + b1v;
    float part = s0 * s0 + s1 * s1;
#pragma unroll
    for (int m = 1; m < 32; m <<= 1) part += __shfl_xor(part, m);
    const float time = sqrtf(1.0f + part);     // 1/C_ATTN = 1
    const int dr   = (r & 3) + 8 * (r >> 2) + 4 * hi;
    const int rowg = row0 + dr;
    const int b = rowg >> 11, n = rowg & 2047;
    const int bh = b * 8 + h;
    if (T == 0) {
      u16* q = Qb + ((size_t)bh * Nn + n) * QP;
      q[lo]      = f2bf(alpha * s0);
      q[32 + lo] = f2bf(alpha * s1);
      if (lo == 0)  q[64] = f2bf(alpha * time);
      if (lo < 15)  q[65 + lo] = 0;
    } else if (T == 1) {
      u16* k = Ktl + (size_t)bh * 64 * KTS + (size_t)(n >> 5) * KTS + (size_t)(n & 31) * KROW;
      k[lo]      = f2bf(s0);
      k[32 + lo] = f2bf(s1);
      if (lo == 0)  k[64] = f2bf(-(time - 1.0f));   // centered time, softmax-inv
      if (lo < 15)  k[65 + lo] = 0;                 // u16 65..79 read by MFMA (Q side zero too)
      // u16 80..87 + tile tail: staged to LDS but never ds_read -> leave
    } else {
      u16* v = Vtl + (size_t)bh * 64 * VTS + (size_t)(n >> 5) * VTS + (n & 31);
      v[(size_t)lo * VROW]        = f2bf(s0);
      v[(size_t)(32 + lo) * VROW] = f2bf(s1);
      if (lo == 0) v[(size_t)64 * VROW] = f2bf(time);
      // dims 65..95 + row pads: finite garbage only feeds o2[r>0], never stored
    }
  }
}

// ---------------------------------------------------------------------------
// One 32-key tile (2-phase): issue gload_lds for NEXT tile into (kn,vn),
// compute current tile from (kl,vl) in LDS, then __syncthreads (drains the
// stage's vmcnt + all ds_reads -> next tile ready, old buffer reusable).
// ---------------------------------------------------------------------------
DEV void tile_body(const u16* __restrict__ kg, const u16* __restrict__ vg,
                   const u16* kl, const u16* vl, u16* kn, u16* vn,
                   const int w, const int lane, const int lo, const int hi,
                   const bf16x8 (&qf)[5],
                   f32x16& o0, f32x16& o1, f32x16& o2) {
  // stage next tile (block-cooperative: wave w takes insts w, w+4, ...)
  for (int i = w; i < 6; i += 4) gload_lds16(kg + i * 512 + lane * 8, kn + i * 512);
  for (int i = w; i < 8; i += 4) gload_lds16(vg + i * 512 + lane * 8, vn + i * 512);

  // QK^T: D[key][q] from LDS (uniform bank coverage: 176B rows)
  f32x16 sc = {};
#pragma unroll
  for (int s = 0; s < 5; ++s) {
    const bf16x8 kf = *(const bf16x8*)&kl[lo * KROW + 16 * s + 8 * hi];
    sc = __builtin_amdgcn_mfma_f32_32x32x16_bf16(kf, qf[s], sc, 0, 0, 0);
  }
  // p = 2^score (log2e folded into Q's alpha); no max, no denominator
  float p[16];
#pragma unroll
  for (int r = 0; r < 16; ++r) p[r] = FEXP2(sc[r]);
  // P -> bf16 via v_cvt_pk; partner (lane^32) exchange, send-side select
  u32 wA[4], wB[4];
#pragma unroll
  for (int j = 0; j < 4; ++j) {
    wA[j] = cvtpk(p[2 * j], p[2 * j + 1]);
    wB[j] = cvtpk(p[8 + 2 * j], p[8 + 2 * j + 1]);
  }
  const u32 sA0 = hi ? wA[0] : wA[2], sA1 = hi ? wA[1] : wA[3];
  const u32 sB0 = hi ? wB[0] : wB[2], sB1 = hi ? wB[1] : wB[3];
  const u32 rA0 = (u32)__shfl_xor((int)sA0, 32);
  const u32 rA1 = (u32)__shfl_xor((int)sA1, 32);
  const u32 rB0 = (u32)__shfl_xor((int)sB0, 32);
  const u32 rB1 = (u32)__shfl_xor((int)sB1, 32);
  u32x4 ua = hi ? (u32x4){rA0, rA1, wA[2], wA[3]}
                : (u32x4){wA[0], wA[1], rA0, rA1};
  u32x4 ub = hi ? (u32x4){rB0, rB1, wB[2], wB[3]}
                : (u32x4){wB[0], wB[1], rB0, rB1};
  union { u32x4 u; bf16x8 b; } ca, cb;
  ca.u = ua; cb.u = ub;
  const bf16x8 fA = ca.b;   // keys +0..15
  const bf16x8 fB = cb.b;   // keys +16..31
  // PV: O^T[d][q] += V^T[d][key] * P^T[key][q], V from LDS (80B rows)
#pragma unroll
  for (int t = 0; t < 3; ++t) {
    const bf16x8 va = *(const bf16x8*)&vl[(32 * t + lo) * VROW + 8 * hi];
    const bf16x8 vb = *(const bf16x8*)&vl[(32 * t + lo) * VROW + 16 + 8 * hi];
    f32x16& ot = (t == 0 ? o0 : (t == 1 ? o1 : o2));
    ot = __builtin_amdgcn_mfma_f32_32x32x16_bf16(va, fA, ot, 0, 0, 0);
    ot = __builtin_amdgcn_mfma_f32_32x32x16_bf16(vb, fB, ot, 0, 0, 0);
  }
  __syncthreads();   // drains stage vmcnt + ds_reads (HIP barrier semantics)
}

// ---------------------------------------------------------------------------
// Attention (no-max softmax; scale-invariant normalize -> no denominator).
// 4 waves/block share LDS-staged K/V tiles; 1 wave = 32 q, swapped QK^T.
// XCD-chunked swizzle. S=4 K-splits. Partials: part[(bh*4+s)*2048+n][72].
// ---------------------------------------------------------------------------
__global__ __launch_bounds__(256) void attn_k(
    const u16* __restrict__ Qb, const u16* __restrict__ Ktl,
    const u16* __restrict__ Vtl, u16* __restrict__ part) {
  __shared__ u16 kls[2][KTS];
  __shared__ u16 vls[2][VTS];

  const int tid  = threadIdx.x;
  const int w    = tid >> 6, lane = tid & 63;
  const int lo   = lane & 31, hi = lane >> 5;

  // XCD-chunked swizzle (2048 blocks, 8 XCDs, bijective): 4 whole bh per XCD
  const u32 bid = blockIdx.x;
  const u32 swz = (bid & 7) * 256 + (bid >> 3);
  const int bh   = swz >> 6;
  const int sidx = (swz >> 4) & 3;
  const int qt   = swz & 15;
  const int qbase = qt * 128 + w * 32;

  const u16* qrow = Qb + ((size_t)bh * Nn + qbase + lo) * QP;
  bf16x8 qf[5];
#pragma unroll
  for (int s = 0; s < 5; ++s) qf[s] = *(const bf16x8*)&qrow[16 * s + 8 * hi];

  f32x16 o0 = {}, o1 = {}, o2 = {};   // O^T rows d = 0..31, 32..63, 64..95
  const u16* ktb = Ktl + (size_t)bh * 64 * KTS + (size_t)(sidx * 16) * KTS;
  const u16* vtb = Vtl + (size_t)bh * 64 * VTS + (size_t)(sidx * 16) * VTS;

  // prologue: stage tile 0 into buffer 0
  for (int i = w; i < 6; i += 4) gload_lds16(ktb + i * 512 + lane * 8, &kls[0][i * 512]);
  for (int i = w; i < 8; i += 4) gload_lds16(vtb + i * 512 + lane * 8, &vls[0][i * 512]);
  __syncthreads();

  for (int it = 0; it < 8; ++it) {
    const int tA = 2 * it + 1;                              // staged during body A
    const int tB = (2 * it + 2 < 16) ? 2 * it + 2 : 15;     // staged during body B (last: redundant)
    tile_body(ktb + (size_t)tA * KTS, vtb + (size_t)tA * VTS,
              kls[0], vls[0], kls[1], vls[1], w, lane, lo, hi, qf, o0, o1, o2);
    tile_body(ktb + (size_t)tB * KTS, vtb + (size_t)tB * VTS,
              kls[1], vls[1], kls[0], vls[0], w, lane, lo, hi, qf, o0, o1, o2);
  }

  // write raw partial O^T, d-contiguous rows: lane owns q = qbase+lo.
  const int q = qbase + lo;
  u16* po = part + ((size_t)((bh * NS + sidx) * Nn + q)) * PR;
#pragma unroll
  for (int t = 0; t < 4; ++t) {
    const u32 a0 = cvtpk(o0[4 * t], o0[4 * t + 1]);
    const u32 a1 = cvtpk(o0[4 * t + 2], o0[4 * t + 3]);
    const u32 b0 = cvtpk(o1[4 * t], o1[4 * t + 1]);
    const u32 b1 = cvtpk(o1[4 * t + 2], o1[4 * t + 3]);
    *(u32x2*)&po[8 * t + 4 * hi]      = (u32x2){a0, a1};
    *(u32x2*)&po[8 * t + 4 * hi + 32] = (u32x2){b0, b1};
  }
  if (hi == 0) po[64] = f2bf(o2[0]);
}

// ---------------------------------------------------------------------------
// Finale (wave-cooperative): one wave per (b,n). Lane l -> (h = l>>3, chunk
// c = l&7). Combine 4 splits, per-head Lorentz normalize (shfl_xor 1,2,4),
// head-sum (shfl_xor 8,16,32), final normalize + re-lift.
// ---------------------------------------------------------------------------
__global__ __launch_bounds__(256) void finale_k(const u16* __restrict__ part,
                                                float* __restrict__ out) {
  const int tid = threadIdx.x;
  const int wv = tid >> 6, l = tid & 63;
  const int g = blockIdx.x * 4 + wv;       // 0..8191 = b*2048+n
  const int b = g >> 11, n = g & 2047;
  const int h = l >> 3, c = l & 7;

  const u16* rowp = part + ((size_t)((b * 8 + h) * NS) * Nn + n) * PR;
  float Oh[8];
#pragma unroll
  for (int j = 0; j < 8; ++j) Oh[j] = 0.f;
  float th = 0.f;
#pragma unroll
  for (int s = 0; s < NS; ++s) {
    const u16* rp = rowp + (size_t)s * Nn * PR;
    const u32x4 v = *(const u32x4*)&rp[8 * c];
#pragma unroll
    for (int i = 0; i < 4; ++i) {
      union { u32 u; float f; } a, bb;
      a.u  = v[i] << 16;
      bb.u = v[i] & 0xffff0000u;
      Oh[2 * i]     += a.f;
      Oh[2 * i + 1] += bb.f;
    }
    th += bf2f(rp[64]);
  }

  float sq = 0.f;
#pragma unroll
  for (int j = 0; j < 8; ++j) sq += Oh[j] * Oh[j];
  sq += __shfl_xor(sq, 1);
  sq += __shfl_xor(sq, 2);
  sq += __shfl_xor(sq, 4);
  const float invh = rsqrtf(fmaxf(th * th - sq, 1e-7f));

  float S[8];
#pragma unroll
  for (int j = 0; j < 8; ++j) S[j] = Oh[j] * invh;
  float T = th * invh;
#pragma unroll
  for (int m = 8; m <= 32; m <<= 1) {
#pragma unroll
    for (int j = 0; j < 8; ++j) S[j] += __shfl_xor(S[j], m);
    T += __shfl_xor(T, m);
  }

  float s2 = 0.f;
#pragma unroll
  for (int j = 0; j < 8; ++j) s2 += S[j] * S[j];
  s2 += __shfl_xor(s2, 1);
  s2 += __shfl_xor(s2, 2);
  s2 += __shfl_xor(s2, 4);
  const float inv = rsqrtf(fmaxf(T * T - s2, 1e-7f));
  const float ssp = s2 * inv * inv;        // ||spatial_out||^2

  float* o = out + (size_t)g * AMB;
  if (h == 0) {
#pragma unroll
    for (int j = 0; j < 8; ++j) o[1 + 8 * c + j] = S[j] * inv;
    if (l == 0) o[0] = sqrtf(1.0f + ssp);
  }
}

// ---------------------------------------------------------------------------
extern "C" void kernel_launch(void* const* d_in, const int* in_sizes, int n_in,
                              void* d_out, int out_size, void* d_ws, size_t ws_size,
                              hipStream_t stream) {
  (void)in_sizes; (void)n_in; (void)out_size; (void)ws_size;
  const float* x  = (const float*)d_in[0];
  const float* Wq = (const float*)d_in[1];
  const float* Wk = (const float*)d_in[2];
  const float* Wv = (const float*)d_in[3];
  const float* bq = (const float*)d_in[4];
  const float* bk = (const float*)d_in[5];
  const float* bv = (const float*)d_in[6];
  const float* sc = (const float*)d_in[7];
  // d_in[8] = attn_bias: uniform additive score offset -> softmax-invariant.

  char* ws = (char*)d_ws;
  u16*  Qb  = (u16*)(ws);                  // 10,485,760 B
  u16*  Ktl = (u16*)(ws + 10485760);       // 32*64*6144 = 12,582,912 B
  u16*  Vtl = (u16*)(ws + 23068672);       // 32*64*8192 = 16,777,216 B
  u16*  pb  = (u16*)(ws + 39845888);       // bf16 partials: 37,748,736 B -> end 77.6 MB
  u16*  xb  = (u16*)(ws + 39845888);       // 2,359,296 B overlay, dead before attn_k
  float* out = (float*)d_out;

  hipLaunchKernelGGL(prep_k, dim3(576), dim3(256), 0, stream, x, xb);
  hipLaunchKernelGGL(proj_k, dim3(64, 24), dim3(256), 0, stream,
                     xb, Wq, Wk, Wv, bq, bk, bv, sc, Qb, Ktl, Vtl);
  hipLaunchKernelGGL(attn_k, dim3(2048), dim3(256), 0, stream, Qb, Ktl, Vtl, pb);
  hipLaunchKernelGGL(finale_k, dim3(2048), dim3(256), 0, stream, pb, out);
}

// Round 9
// 120.000 us; speedup vs baseline: 3.5312x; 1.0016x over previous
//
#include <hip/hip_runtime.h>
#include <hip/hip_bf16.h>

typedef __bf16 bf16x8 __attribute__((ext_vector_type(8)));
typedef float f32x16 __attribute__((ext_vector_type(16)));
typedef unsigned int u32;
typedef unsigned short u16;
typedef u32 u32x2 __attribute__((ext_vector_type(2)));
typedef u32 u32x4 __attribute__((ext_vector_type(4)));

static constexpr int Nn  = 2048;
static constexpr int DIN = 129;   // in_features = D_IN+1
static constexpr int QP  = 80;    // padded q/k width (65 -> 80)
static constexpr int AMB = 65;    // ambient dim
static constexpr int XP  = 144;   // padded x row (129 -> 144)
static constexpr int NS  = 4;     // K-splits
static constexpr int PR  = 72;    // partial row pad (65 -> 72), 144 B
// Tiled K/V global layouts == LDS image (gload_lds linear-dest constraint):
static constexpr int KROW = 88;   // K tile row, u16 (176 B)
static constexpr int KTS  = 3072; // K tile size, u16 (6144 B = 6 x 1024B insts)
static constexpr int VROW = 40;   // V tile row, u16 (80 B)
static constexpr int VTS  = 4096; // V tile size, u16 (8192 B = 8 x 1024B insts)
static constexpr float LOG2E = 1.4426950408889634f;

#define DEV static __device__ __forceinline__

#if __has_builtin(__builtin_amdgcn_exp2f)
#define FEXP2 __builtin_amdgcn_exp2f
#else
#define FEXP2 exp2f
#endif

DEV u16 f2bf(float f) {
  union { __bf16 h; u16 u; } c;
  c.h = (__bf16)f;
  return c.u;
}
DEV float bf2f(u16 u) {
  union { float f; u32 uu; } c;
  c.uu = ((u32)u) << 16;
  return c.f;
}
DEV u32 cvtpk(float a, float b) {   // low16 = bf16(a), high16 = bf16(b)
  u32 r;
  asm("v_cvt_pk_bf16_f32 %0, %1, %2" : "=v"(r) : "v"(a), "v"(b));
  return r;
}
DEV void gload_lds16(const u16* g, u16* l) {   // 64 lanes x 16B -> 1024B linear LDS
  __builtin_amdgcn_global_load_lds(
      (const __attribute__((address_space(1))) unsigned int*)g,
      (__attribute__((address_space(3))) unsigned int*)l, 16, 0, 0);
}

// ---------------------------------------------------------------------------
// Prep: x (f32 [8192][129]) -> xb (bf16 [8192][144], zero-padded, 16B-aligned)
// ---------------------------------------------------------------------------
__global__ __launch_bounds__(256) void prep_k(const float* __restrict__ x,
                                              u16* __restrict__ xb) {
  const int t = blockIdx.x * 256 + threadIdx.x;   // 0 .. 8192*18-1
  const int row = t / 18, cg = t % 18;
  u16 tmp[8];
#pragma unroll
  for (int j = 0; j < 8; ++j) {
    const int c = cg * 8 + j;
    tmp[j] = (c < DIN) ? f2bf(x[(size_t)row * DIN + c]) : (u16)0;
  }
  u32x4 w;
  w[0] = (u32)tmp[0] | ((u32)tmp[1] << 16);
  w[1] = (u32)tmp[2] | ((u32)tmp[3] << 16);
  w[2] = (u32)tmp[4] | ((u32)tmp[5] << 16);
  w[3] = (u32)tmp[6] | ((u32)tmp[7] << 16);
  *((u32x4*)xb + t) = w;
}

// ---------------------------------------------------------------------------
// Projection: s = xb @ W[h] + b, lift (C_ATTN=1). Epilogue: scatter into a
// per-wave LDS tile (global-layout image), then coalesced b128 copy-out.
//   Qb:  [bh][n][80] bf16 = alpha' * [qs(64), q0], alpha' = 2*log2e/(scale+eps)
//   Ktl: [bh][tile][key][88] bf16 = [ks(64), -(k0-1), 0*15, junk*8]
//   Vtl: [bh][tile][dim][40] bf16 = col n&31; dims 0-63 vs, 64 v0; rows 65+ junk
// ---------------------------------------------------------------------------
__global__ __launch_bounds__(256) void proj_k(
    const u16* __restrict__ xb,
    const float* __restrict__ Wq, const float* __restrict__ Wk, const float* __restrict__ Wv,
    const float* __restrict__ bq, const float* __restrict__ bk, const float* __restrict__ bv,
    const float* __restrict__ scale_p,
    u16* __restrict__ Qb, u16* __restrict__ Ktl, u16* __restrict__ Vtl) {
  __shared__ u16 wt[64][152];                       // W^T: [d][k]
  __shared__ __align__(16) u16 tiles[4][2816];      // per-wave output tile image

  const int tid = threadIdx.x;
  const int wid = tid >> 6, l = tid & 63;
  const int z = blockIdx.y;            // 0..23
  const int T = z >> 3, h = z & 7;     // tensor (0=Q,1=K,2=V), head
  const float* W    = (T == 0 ? Wq : (T == 1 ? Wk : Wv)) + (size_t)h * DIN * 64;
  const float* bias = (T == 0 ? bq : (T == 1 ? bk : bv)) + h * 64;

  {
    const int d = tid & 63, kk = tid >> 6;
    for (int k = kk; k < XP; k += 4)
      wt[d][k] = (k < DIN) ? f2bf(W[(size_t)k * 64 + d]) : (u16)0;
  }
  __syncthreads();

  const int lo = l & 31, hi = l >> 5;
  const int row0 = (blockIdx.x * 4 + wid) * 32;
  const u16* xr = xb + (size_t)(row0 + lo) * XP;

  f32x16 acc0 = {}, acc1 = {};
#pragma unroll
  for (int s = 0; s < 9; ++s) {
    bf16x8 a  = *(const bf16x8*)&xr[16 * s + 8 * hi];
    bf16x8 b0 = *(const bf16x8*)&wt[lo][16 * s + 8 * hi];
    bf16x8 b1 = *(const bf16x8*)&wt[32 + lo][16 * s + 8 * hi];
    acc0 = __builtin_amdgcn_mfma_f32_32x32x16_bf16(a, b0, acc0, 0, 0, 0);
    acc1 = __builtin_amdgcn_mfma_f32_32x32x16_bf16(a, b1, acc1, 0, 0, 0);
  }
  const float b0v = bias[lo], b1v = bias[32 + lo];
  const float alpha = 2.0f * LOG2E / (scale_p[0] + 1e-7f);
  u16* tl = &tiles[wid][0];

#pragma unroll
  for (int r = 0; r < 16; ++r) {
    const float s0 = acc0[r] + b0v;
    const float s1 = acc1[r] + b1v;
    float part = s0 * s0 + s1 * s1;
#pragma unroll
    for (int m = 1; m < 32; m <<= 1) part += __shfl_xor(part, m);
    const float time = sqrtf(1.0f + part);     // 1/C_ATTN = 1
    const int dr = (r & 3) + 8 * (r >> 2) + 4 * hi;   // row within 32-row tile
    if (T == 0) {
      tl[dr * 80 + lo]      = f2bf(alpha * s0);
      tl[dr * 80 + 32 + lo] = f2bf(alpha * s1);
      if (lo == 0) tl[dr * 80 + 64] = f2bf(alpha * time);
      if (lo < 15) tl[dr * 80 + 65 + lo] = 0;
    } else if (T == 1) {
      tl[dr * 88 + lo]      = f2bf(s0);
      tl[dr * 88 + 32 + lo] = f2bf(s1);
      if (lo == 0) tl[dr * 88 + 64] = f2bf(-(time - 1.0f));  // centered time
      if (lo < 15) tl[dr * 88 + 65 + lo] = 0;
      if (lo < 8)  tl[dr * 88 + 80 + lo] = 0;   // keep copied bytes defined
    } else {
      tl[lo * 40 + dr]        = f2bf(s0);
      tl[(32 + lo) * 40 + dr] = f2bf(s1);
      if (lo == 0) tl[64 * 40 + dr] = f2bf(time);
      if (lo < 8)  tl[lo * 40 + 32 + dr >= 0 ? (lo * 40 + 32 + (dr & 7)) : 0] = tl[lo * 40 + 32 + (dr & 7)]; // no-op placeholder
    }
  }
  __syncthreads();   // per-wave tile, but cheap certainty for LDS write->read

  // coalesced copy-out: 16B chunks
  const int b = row0 >> 11, n0 = row0 & 2047;
  const int bh = b * 8 + h;
  u16* gdst;
  int nch;
  if (T == 0) { gdst = Qb + ((size_t)bh * Nn + n0) * QP;                nch = 320; }
  else if (T == 1) { gdst = Ktl + (size_t)bh * 64 * KTS + (size_t)(n0 >> 5) * KTS; nch = 352; }
  else { gdst = Vtl + (size_t)bh * 64 * VTS + (size_t)(n0 >> 5) * VTS;  nch = 325; }
  for (int j = l; j < nch; j += 64)
    *(u32x4*)(gdst + j * 8) = *(const u32x4*)(tl + j * 8);
}

// ---------------------------------------------------------------------------
// attn staging: 14 gload_lds insts/tile split 4/4/3/3 across waves
// ---------------------------------------------------------------------------
DEV void stage_tile(const u16* kg, const u16* vg, u16* kl, u16* vl,
                    const int w, const int lane) {
  if (w < 2) {
#pragma unroll
    for (int i = 0; i < 3; ++i)
      gload_lds16(kg + (w * 3 + i) * 512 + lane * 8, kl + (w * 3 + i) * 512);
    gload_lds16(vg + w * 512 + lane * 8, vl + w * 512);
  } else {
#pragma unroll
    for (int i = 0; i < 3; ++i) {
      const int j = (w - 2) * 3 + 2 + i;     // 2..4 / 5..7
      gload_lds16(vg + j * 512 + lane * 8, vl + j * 512);
    }
  }
}

// T4 counted-vmcnt barrier: leave the newest tile's own loads (4 or 3) in
// flight, drain everything older + all lgkm. One asm block so no memory op
// can be scheduled between the waitcnt and the barrier.
DEV void waitbar(const int w) {
  if (w < 2)
    asm volatile("s_waitcnt vmcnt(4) lgkmcnt(0)\ns_barrier" ::: "memory");
  else
    asm volatile("s_waitcnt vmcnt(3) lgkmcnt(0)\ns_barrier" ::: "memory");
}

// ---------------------------------------------------------------------------
// One 32-key tile compute from LDS: QK^T, exp2, cvt_pk + partner exchange, PV.
// ---------------------------------------------------------------------------
DEV void compute_tile(const u16* kl, const u16* vl, const int lo, const int hi,
                      const bf16x8 (&qf)[5],
                      f32x16& o0, f32x16& o1, f32x16& o2) {
  f32x16 sc = {};
#pragma unroll
  for (int s = 0; s < 5; ++s) {
    const bf16x8 kf = *(const bf16x8*)&kl[lo * KROW + 16 * s + 8 * hi];
    sc = __builtin_amdgcn_mfma_f32_32x32x16_bf16(kf, qf[s], sc, 0, 0, 0);
  }
  float p[16];
#pragma unroll
  for (int r = 0; r < 16; ++r) p[r] = FEXP2(sc[r]);
  u32 wA[4], wB[4];
#pragma unroll
  for (int j = 0; j < 4; ++j) {
    wA[j] = cvtpk(p[2 * j], p[2 * j + 1]);
    wB[j] = cvtpk(p[8 + 2 * j], p[8 + 2 * j + 1]);
  }
  const u32 sA0 = hi ? wA[0] : wA[2], sA1 = hi ? wA[1] : wA[3];
  const u32 sB0 = hi ? wB[0] : wB[2], sB1 = hi ? wB[1] : wB[3];
  const u32 rA0 = (u32)__shfl_xor((int)sA0, 32);
  const u32 rA1 = (u32)__shfl_xor((int)sA1, 32);
  const u32 rB0 = (u32)__shfl_xor((int)sB0, 32);
  const u32 rB1 = (u32)__shfl_xor((int)sB1, 32);
  u32x4 ua = hi ? (u32x4){rA0, rA1, wA[2], wA[3]}
                : (u32x4){wA[0], wA[1], rA0, rA1};
  u32x4 ub = hi ? (u32x4){rB0, rB1, wB[2], wB[3]}
                : (u32x4){wB[0], wB[1], rB0, rB1};
  union { u32x4 u; bf16x8 b; } ca, cb;
  ca.u = ua; cb.u = ub;
  const bf16x8 fA = ca.b;   // keys +0..15
  const bf16x8 fB = cb.b;   // keys +16..31
#pragma unroll
  for (int t = 0; t < 3; ++t) {
    const bf16x8 va = *(const bf16x8*)&vl[(32 * t + lo) * VROW + 8 * hi];
    const bf16x8 vb = *(const bf16x8*)&vl[(32 * t + lo) * VROW + 16 + 8 * hi];
    f32x16& ot = (t == 0 ? o0 : (t == 1 ? o1 : o2));
    ot = __builtin_amdgcn_mfma_f32_32x32x16_bf16(va, fA, ot, 0, 0, 0);
    ot = __builtin_amdgcn_mfma_f32_32x32x16_bf16(vb, fB, ot, 0, 0, 0);
  }
}

// ---------------------------------------------------------------------------
// Attention: triple-buffered LDS staging, depth-2 prefetch, counted vmcnt.
// 4 waves/block, 1 wave = 32 q, swapped QK^T. XCD-chunked swizzle. S=4 splits.
// ---------------------------------------------------------------------------
__global__ __launch_bounds__(256) void attn_k(
    const u16* __restrict__ Qb, const u16* __restrict__ Ktl,
    const u16* __restrict__ Vtl, u16* __restrict__ part) {
  __shared__ u16 kls[3][KTS];
  __shared__ u16 vls[3][VTS];

  const int tid  = threadIdx.x;
  const int w    = tid >> 6, lane = tid & 63;
  const int lo   = lane & 31, hi = lane >> 5;

  // XCD-chunked swizzle (2048 blocks, 8 XCDs, bijective): 4 whole bh per XCD
  const u32 bid = blockIdx.x;
  const u32 swz = (bid & 7) * 256 + (bid >> 3);
  const int bh   = swz >> 6;
  const int sidx = (swz >> 4) & 3;
  const int qt   = swz & 15;
  const int qbase = qt * 128 + w * 32;

  const u16* qrow = Qb + ((size_t)bh * Nn + qbase + lo) * QP;
  bf16x8 qf[5];
#pragma unroll
  for (int s = 0; s < 5; ++s) qf[s] = *(const bf16x8*)&qrow[16 * s + 8 * hi];

  f32x16 o0 = {}, o1 = {}, o2 = {};   // O^T rows d = 0..31, 32..63, 64..95
  const u16* ktb = Ktl + (size_t)bh * 64 * KTS + (size_t)(sidx * 16) * KTS;
  const u16* vtb = Vtl + (size_t)bh * 64 * VTS + (size_t)(sidx * 16) * VTS;

  // prologue: prefetch tiles 0 and 1
  stage_tile(ktb, vtb, kls[0], vls[0], w, lane);
  stage_tile(ktb + KTS, vtb + VTS, kls[1], vls[1], w, lane);
  waitbar(w);   // tile 0 landed everywhere; tile 1 in flight

  for (int t = 0; t < 16; ++t) {
    const int pf = (t + 2 < 16) ? t + 2 : 15;   // clamp: redundant restage keeps vmcnt math uniform
    stage_tile(ktb + (size_t)pf * KTS, vtb + (size_t)pf * VTS,
               kls[(t + 2) % 3], vls[(t + 2) % 3], w, lane);
    compute_tile(kls[t % 3], vls[t % 3], lo, hi, qf, o0, o1, o2);
    waitbar(w);  // tile t+1 landed; tile t+2 in flight
  }

  // write raw partial O^T, d-contiguous rows: lane owns q = qbase+lo.
  const int q = qbase + lo;
  u16* po = part + ((size_t)((bh * NS + sidx) * Nn + q)) * PR;
#pragma unroll
  for (int t = 0; t < 4; ++t) {
    const u32 a0 = cvtpk(o0[4 * t], o0[4 * t + 1]);
    const u32 a1 = cvtpk(o0[4 * t + 2], o0[4 * t + 3]);
    const u32 b0 = cvtpk(o1[4 * t], o1[4 * t + 1]);
    const u32 b1 = cvtpk(o1[4 * t + 2], o1[4 * t + 3]);
    *(u32x2*)&po[8 * t + 4 * hi]      = (u32x2){a0, a1};
    *(u32x2*)&po[8 * t + 4 * hi + 32] = (u32x2){b0, b1};
  }
  if (hi == 0) po[64] = f2bf(o2[0]);
}

// ---------------------------------------------------------------------------
// Finale (wave-cooperative): one wave per (b,n). Lane l -> (h = l>>3, chunk
// c = l&7). Combine 4 splits, per-head Lorentz normalize (shfl_xor 1,2,4),
// head-sum (shfl_xor 8,16,32), final normalize + re-lift.
// ---------------------------------------------------------------------------
__global__ __launch_bounds__(256) void finale_k(const u16* __restrict__ part,
                                                float* __restrict__ out) {
  const int tid = threadIdx.x;
  const int wv = tid >> 6, l = tid & 63;
  const int g = blockIdx.x * 4 + wv;       // 0..8191 = b*2048+n
  const int b = g >> 11, n = g & 2047;
  const int h = l >> 3, c = l & 7;

  const u16* rowp = part + ((size_t)((b * 8 + h) * NS) * Nn + n) * PR;
  float Oh[8];
#pragma unroll
  for (int j = 0; j < 8; ++j) Oh[j] = 0.f;
  float th = 0.f;
#pragma unroll
  for (int s = 0; s < NS; ++s) {
    const u16* rp = rowp + (size_t)s * Nn * PR;
    const u32x4 v = *(const u32x4*)&rp[8 * c];
#pragma unroll
    for (int i = 0; i < 4; ++i) {
      union { u32 u; float f; } a, bb;
      a.u  = v[i] << 16;
      bb.u = v[i] & 0xffff0000u;
      Oh[2 * i]     += a.f;
      Oh[2 * i + 1] += bb.f;
    }
    th += bf2f(rp[64]);
  }

  float sq = 0.f;
#pragma unroll
  for (int j = 0; j < 8; ++j) sq += Oh[j] * Oh[j];
  sq += __shfl_xor(sq, 1);
  sq += __shfl_xor(sq, 2);
  sq += __shfl_xor(sq, 4);
  const float invh = rsqrtf(fmaxf(th * th - sq, 1e-7f));

  float S[8];
#pragma unroll
  for (int j = 0; j < 8; ++j) S[j] = Oh[j] * invh;
  float T = th * invh;
#pragma unroll
  for (int m = 8; m <= 32; m <<= 1) {
#pragma unroll
    for (int j = 0; j < 8; ++j) S[j] += __shfl_xor(S[j], m);
    T += __shfl_xor(T, m);
  }

  float s2 = 0.f;
#pragma unroll
  for (int j = 0; j < 8; ++j) s2 += S[j] * S[j];
  s2 += __shfl_xor(s2, 1);
  s2 += __shfl_xor(s2, 2);
  s2 += __shfl_xor(s2, 4);
  const float inv = rsqrtf(fmaxf(T * T - s2, 1e-7f));
  const float ssp = s2 * inv * inv;        // ||spatial_out||^2

  float* o = out + (size_t)g * AMB;
  if (h == 0) {
#pragma unroll
    for (int j = 0; j < 8; ++j) o[1 + 8 * c + j] = S[j] * inv;
    if (l == 0) o[0] = sqrtf(1.0f + ssp);
  }
}

// ---------------------------------------------------------------------------
extern "C" void kernel_launch(void* const* d_in, const int* in_sizes, int n_in,
                              void* d_out, int out_size, void* d_ws, size_t ws_size,
                              hipStream_t stream) {
  (void)in_sizes; (void)n_in; (void)out_size; (void)ws_size;
  const float* x  = (const float*)d_in[0];
  const float* Wq = (const float*)d_in[1];
  const float* Wk = (const float*)d_in[2];
  const float* Wv = (const float*)d_in[3];
  const float* bq = (const float*)d_in[4];
  const float* bk = (const float*)d_in[5];
  const float* bv = (const float*)d_in[6];
  const float* sc = (const float*)d_in[7];
  // d_in[8] = attn_bias: uniform additive score offset -> softmax-invariant.

  char* ws = (char*)d_ws;
  u16*  Qb  = (u16*)(ws);                  // 10,485,760 B
  u16*  Ktl = (u16*)(ws + 10485760);       // 32*64*6144 = 12,582,912 B
  u16*  Vtl = (u16*)(ws + 23068672);       // 32*64*8192 = 16,777,216 B
  u16*  pb  = (u16*)(ws + 39845888);       // bf16 partials: 37,748,736 B -> end 77.6 MB
  u16*  xb  = (u16*)(ws + 39845888);       // 2,359,296 B overlay, dead before attn_k
  float* out = (float*)d_out;

  hipLaunchKernelGGL(prep_k, dim3(576), dim3(256), 0, stream, x, xb);
  hipLaunchKernelGGL(proj_k, dim3(64, 24), dim3(256), 0, stream,
                     xb, Wq, Wk, Wv, bq, bk, bv, sc, Qb, Ktl, Vtl);
  hipLaunchKernelGGL(attn_k, dim3(2048), dim3(256), 0, stream, Qb, Ktl, Vtl, pb);
  hipLaunchKernelGGL(finale_k, dim3(2048), dim3(256), 0, stream, pb, out);
}